// Round 9
// baseline (130.032 us; speedup 1.0000x reference)
//
#include <hip/hip_runtime.h>
#include <stdint.h>

#define N 8192
#define D 256          // elements per row == bytes per fp8 row
#define INV_T 20.0f
#define LOG2E 1.44269504088896340736f
#define BM 128
#define BN 128
#define NXB 64         // col-blocks (N/BN)

typedef __attribute__((ext_vector_type(16))) float f32x16;
typedef __attribute__((ext_vector_type(4))) int i32x4;
typedef __attribute__((ext_vector_type(8))) int i32x8;

typedef __attribute__((address_space(3))) uint32_t lds_u32;
typedef __attribute__((address_space(1))) const uint32_t gbl_u32;

// Raw v_exp_f32 (2^x). Library exp2f carries a multi-instruction guard for
// |x|>~126; our args are bounded, so the raw trans op is safe (verified r5).
static __device__ __forceinline__ float fast_exp2(float x) {
  float r;
  asm("v_exp_f32 %0, %1" : "=v"(r) : "v"(x));
  return r;
}

// DPP-fused butterfly add levels (bit-identical to __shfl_xor tree, r4/r5).
#define DPP_ADD(v, ctrl)                                                      \
  ((v) + __builtin_bit_cast(float, __builtin_amdgcn_update_dpp(               \
             0, __builtin_bit_cast(int, (v)), (ctrl), 0xf, 0xf, true)))

// Kernel 1: per-row fp32 normalize -> fp8 e4m3 copies (HW cvt, OCP on gfx950);
// c[i] = (e_i . p_i)/T exact fp32. Zeroes out (stream-ordered; replay-safe).
__global__ __launch_bounds__(256) void normalize_kernel(
    const float* __restrict__ e, const float* __restrict__ p, const float* __restrict__ n,
    uint32_t* __restrict__ eb, uint32_t* __restrict__ pb, uint32_t* __restrict__ nb,
    float* __restrict__ cbuf, float* __restrict__ out) {
  const int tid = threadIdx.x;
  const int wave = tid >> 6, lane = tid & 63;
  const int row = blockIdx.x * 4 + wave;          // one wave per row

  if (blockIdx.x == 0 && tid == 0) out[0] = 0.0f;

  const float4 ev = ((const float4*)(e + (size_t)row * D))[lane];
  const float4 pv = ((const float4*)(p + (size_t)row * D))[lane];
  const float4 nv = ((const float4*)(n + (size_t)row * D))[lane];

  float sse = ev.x*ev.x + ev.y*ev.y + ev.z*ev.z + ev.w*ev.w;
  float ssp = pv.x*pv.x + pv.y*pv.y + pv.z*pv.z + pv.w*pv.w;
  float ssn = nv.x*nv.x + nv.y*nv.y + nv.z*nv.z + nv.w*nv.w;
  float dep = ev.x*pv.x + ev.y*pv.y + ev.z*pv.z + ev.w*pv.w;
#pragma unroll
  for (int m = 1; m < 64; m <<= 1) {
    sse += __shfl_xor(sse, m);
    ssp += __shfl_xor(ssp, m);
    ssn += __shfl_xor(ssn, m);
    dep += __shfl_xor(dep, m);
  }
  const float se = 1.0f / fmaxf(sqrtf(sse), 1e-8f);
  const float sp = 1.0f / fmaxf(sqrtf(ssp), 1e-8f);
  const float sn = 1.0f / fmaxf(sqrtf(ssn), 1e-8f);

  int ue = __builtin_amdgcn_cvt_pk_fp8_f32(ev.x*se, ev.y*se, 0, false);
  ue     = __builtin_amdgcn_cvt_pk_fp8_f32(ev.z*se, ev.w*se, ue, true);
  int up = __builtin_amdgcn_cvt_pk_fp8_f32(pv.x*sp, pv.y*sp, 0, false);
  up     = __builtin_amdgcn_cvt_pk_fp8_f32(pv.z*sp, pv.w*sp, up, true);
  int un = __builtin_amdgcn_cvt_pk_fp8_f32(nv.x*sn, nv.y*sn, 0, false);
  un     = __builtin_amdgcn_cvt_pk_fp8_f32(nv.z*sn, nv.w*sn, un, true);
  eb[row * 64 + lane] = (uint32_t)ue;             // 64 uints = 256 fp8 bytes per row
  pb[row * 64 + lane] = (uint32_t)up;
  nb[row * 64 + lane] = (uint32_t)un;

  if (lane == 0) cbuf[row] = dep * se * sp * INV_T;
}

// Kernel 2: 128x128-tile fp8 GEMM (X @ Y^T) with fused exp row-sums.
// r5 core (58.4 us proven: full-K single-buffer B, ONE barrier, A in regs,
// 16-slot XOR LDS layout = 0 conflicts, scaled MFMA = bit-exact 2x rate,
// raw v_exp_f32, XOR-folded addresses, part-store epilogue) restructured
// NI-MAJOR: finish the 4 K-step MFMAs of one output quadrant, then
// exp-accumulate that quadrant into sums[16] while the next quadrant's
// MFMAs issue -> trans/VALU overlaps MFMA+DS *within* a wave (r5 ran the
// whole epilogue serially after the whole K-loop; VALUBusy was ~100% of
// the measured gap). Same adds in the same order -> bit-identical.
// Side effect: one 16-reg acc live at a time (was 64) -> lower reg pressure.
__global__ __launch_bounds__(256, 3) void simexp_kernel(
    const uint8_t* __restrict__ eb, const uint8_t* __restrict__ pb,
    const uint8_t* __restrict__ nb, const float* __restrict__ cbuf,
    float* __restrict__ part) {
  __shared__ uint8_t Bs[BN * D];    // 32 KB, full-K B tile (swizzled)
  __shared__ float cs[BM];          // 512 B

  const int z = blockIdx.z;
  const uint8_t* __restrict__ A = z ? pb : eb;
  const uint8_t* __restrict__ B = z ? eb : nb;

  const int tid = threadIdx.x;
  const int wave = tid >> 6, lane = tid & 63;
  const int lane31 = lane & 31, half = lane >> 5;
  const int rowTile = blockIdx.x * BM, colblk = blockIdx.y;
  const int colTile = colblk * BN;

  // ---- stage B (full K): 2048 16B chunks, 8 per thread, coalesced ----
#pragma unroll
  for (int i = 0; i < 8; ++i) {
    const int c = i * 256 + tid, r = c >> 4, sl = c & 15;
    const int gg = sl ^ (r & 15);               // swizzled SOURCE group
    __builtin_amdgcn_global_load_lds(
        (gbl_u32*)(B + (size_t)(colTile + r) * D + gg * 16),
        (lds_u32*)&Bs[c * 16], 16, 0, 0);
  }

  // ---- A direct to registers: this lane's row, its K-half, all 4 K-steps ----
  const int arow = rowTile + wave * 32 + lane31;
  const uint8_t* __restrict__ Arow = A + (size_t)arow * D + half * 32;
  i32x8 afr[4];
#pragma unroll
  for (int s = 0; s < 4; ++s) {
    const i32x4 lo = *(const i32x4*)(Arow + s * 64);
    const i32x4 hi = *(const i32x4*)(Arow + s * 64 + 16);
    afr[s] = (i32x8){lo[0], lo[1], lo[2], lo[3], hi[0], hi[1], hi[2], hi[3]};
  }

  if (tid < BM) cs[tid] = cbuf[rowTile + tid] * LOG2E;

  // per-ni XOR-folded B fragment base addresses (byte offsets into Bs)
  int bbase[4];
#pragma unroll
  for (int ni = 0; ni < 4; ++ni) {
    const int cl = ni * 32 + lane31;
    bbase[ni] = (cl << 8) ^ ((cl & 15) << 4) ^ (half << 5);
  }

  __syncthreads();   // the ONLY barrier: B tile + cs visible

  // diag terms per acc reg, hoisted (LDS broadcast reads, once)
  // 32x32 C/D: col=lane&31, row=(reg&3)+8*(reg>>2)+4*(lane>>5) (m74/m101).
  float cv[16];
#pragma unroll
  for (int reg = 0; reg < 16; ++reg)
    cv[reg] = cs[wave * 32 + (reg & 3) + 8 * (reg >> 2) + 4 * half];

  const float K2 = INV_T * LOG2E;
  float sums[16];
#pragma unroll
  for (int reg = 0; reg < 16; ++reg) sums[reg] = 0.0f;

  // ---- NI-MAJOR: per quadrant {4 MFMAs} then {16 exp-accumulates};
  //      exp(ni) is independent of mfma(ni+1) -> pipes overlap in-wave ----
#pragma unroll
  for (int ni = 0; ni < 4; ++ni) {
    f32x16 acc;
#pragma unroll
    for (int r = 0; r < 16; ++r) acc[r] = 0.0f;
#pragma unroll
    for (int s = 0; s < 4; ++s) {
      const int alo = bbase[ni] ^ (s << 6);     // 1 v_xor (s<<6 inline const)
      const i32x4 blo = *(const i32x4*)&Bs[alo];
      const i32x4 bhi = *(const i32x4*)&Bs[alo ^ 16];
      const i32x8 b = (i32x8){blo[0], blo[1], blo[2], blo[3],
                              bhi[0], bhi[1], bhi[2], bhi[3]};
      acc = __builtin_amdgcn_mfma_scale_f32_32x32x64_f8f6f4(
          afr[s], b, acc,
          0 /*A fmt fp8*/, 0 /*B fmt fp8*/,
          0, 0x7F7F7F7F /*scaleA=1*/, 0, 0x7F7F7F7F /*scaleB=1*/);
    }
#pragma unroll
    for (int reg = 0; reg < 16; ++reg)
      sums[reg] += fast_exp2(acc[reg] * K2 - cv[reg]);
  }

  // ---- once per wave: 32-lane butterfly reduce + part store (r5) ----
#pragma unroll
  for (int reg = 0; reg < 16; ++reg) {
    float v = sums[reg];
    v = DPP_ADD(v, 0xB1);    // xor1: quad_perm [1,0,3,2]
    v = DPP_ADD(v, 0x4E);    // xor2: quad_perm [2,3,0,1]
    v = DPP_ADD(v, 0x141);   // xor4: row_half_mirror
    v = DPP_ADD(v, 0x140);   // xor8: row_mirror
    v += __builtin_bit_cast(float, __builtin_amdgcn_ds_swizzle(
             __builtin_bit_cast(int, v), 0x401F));  // xor16
    if (lane31 == 0) {
      const int rowl = wave * 32 + (reg & 3) + 8 * (reg >> 2) + 4 * half;
      part[((size_t)(z * NXB + colblk)) * N + rowTile + rowl] = v;
    }
  }
}

// Kernel 3 (finalize): per-row sum of 64 partials -> log/log1p -> wave reduce
// -> one atomicAdd per 64-thread block (256 atomics to out). No fences needed:
// part is written with plain stores and the launch boundary orders visibility.
__global__ __launch_bounds__(64) void finalize_kernel(const float* __restrict__ part,
                                                      float* __restrict__ out) {
  const int r = blockIdx.x * 64 + threadIdx.x;    // 256 x 64 = 16384 (z,row) pairs
  const int z = r >> 13, row = r & (N - 1);
  float s = 0.0f;
#pragma unroll 8
  for (int x = 0; x < NXB; ++x)
    s += part[((size_t)(z * NXB + x)) * N + row];
  float val = z ? logf(s) : log1pf(s);
#pragma unroll
  for (int m = 1; m < 64; m <<= 1) val += __shfl_xor(val, m);
  if (threadIdx.x == 0) atomicAdd(out, val * (1.0f / (float)N));
}

extern "C" void kernel_launch(void* const* d_in, const int* in_sizes, int n_in,
                              void* d_out, int out_size, void* d_ws, size_t ws_size,
                              hipStream_t stream) {
  const float* e = (const float*)d_in[0];
  const float* p = (const float*)d_in[1];
  const float* n = (const float*)d_in[2];

  char* w = (char*)d_ws;
  uint8_t* eb = (uint8_t*)w;                                     // 2 MB
  uint8_t* pb = eb + (size_t)N * D;                              // 2 MB
  uint8_t* nb = pb + (size_t)N * D;                              // 2 MB
  float* cbuf = (float*)(nb + (size_t)N * D);                    // 32 KB
  float* part = cbuf + N;                                        // 4 MB

  normalize_kernel<<<N / 4, 256, 0, stream>>>(e, p, n, (uint32_t*)eb, (uint32_t*)pb,
                                              (uint32_t*)nb, cbuf, (float*)d_out);
  simexp_kernel<<<dim3(N / BM, N / BN, 2), 256, 0, stream>>>(eb, pb, nb, cbuf, part);
  finalize_kernel<<<256, 64, 0, stream>>>(part, (float*)d_out);
}